// Round 11
// baseline (263.640 us; speedup 1.0000x reference)
//
#include <hip/hip_runtime.h>

// ---------------- problem constants ----------------
#define N_ANCH 221184      // H*W*A = 128*192*9
#define HW     24576       // H*W
#define Wd     192
#define AA     9
#define TOPN   6000
#define POSTN  300
#define NWORDS 94          // ceil(6016/64) removal words (bit per box)
#define NW2    96          // mat row stride in u64 (pad words never written; garbage-safe)
#define NCHUNK 24          // 6144 / 256 scan chunks
#define GRID   512
#define PERBLK 432         // N_ANCH / GRID exactly
#define SEGSZ  1024        // compact segment capacity (8 segs = 8192)

typedef unsigned long long u64;
typedef unsigned int u32;

#define INITTAG 0xBEEF0001u
#define TAGBASE 0xC0DE0000u   // barrier tags; never equals 0xAAAAAAAA poison or 0

// anchor widths/heights (== ws2/hs2 of the reference, exact small ints)
__device__ const float c_aw[9] = {184.f,368.f,736.f,128.f,256.f,512.f, 88.f,176.f,352.f};
__device__ const float c_ah[9] = { 96.f,192.f,384.f,128.f,256.f,512.f,176.f,352.f,704.f};

// ---- agent-scope atomics: bypass L1/L2, L3 is the coherence point ----
__device__ __forceinline__ u32 ald32(const u32* p) {
    return __hip_atomic_load(p, __ATOMIC_RELAXED, __HIP_MEMORY_SCOPE_AGENT);
}
__device__ __forceinline__ void ast32(u32* p, u32 v) {
    __hip_atomic_store(p, v, __ATOMIC_RELAXED, __HIP_MEMORY_SCOPE_AGENT);
}
__device__ __forceinline__ u64 ald64(const u64* p) {
    return __hip_atomic_load(p, __ATOMIC_RELAXED, __HIP_MEMORY_SCOPE_AGENT);
}
__device__ __forceinline__ void ast64(u64* p, u64 v) {
    __hip_atomic_store(p, v, __ATOMIC_RELAXED, __HIP_MEMORY_SCOPE_AGENT);
}
__device__ __forceinline__ void stf4(float4* p, float4 v) {
    u64 lo, hi;
    float2 a = make_float2(v.x, v.y), b = make_float2(v.z, v.w);
    __builtin_memcpy(&lo, &a, 8); __builtin_memcpy(&hi, &b, 8);
    ast64((u64*)p, lo); ast64(((u64*)p) + 1, hi);
}
__device__ __forceinline__ float4 ldf4(const float4* p) {
    u64 lo = ald64((const u64*)p), hi = ald64(((const u64*)p) + 1);
    float2 a, b;
    __builtin_memcpy(&a, &lo, 8); __builtin_memcpy(&b, &hi, 8);
    return make_float4(a.x, a.y, b.x, b.y);
}

// RMW-free grid barrier. Arrivals: one plain agent store per block into its own
// 64B-spaced slot (no same-line serialization). Detection: block 0's 256
// threads poll 2 slots each + __syncthreads_and. Release: one flag store;
// waiters poll exact-match tag. Exact-match tags make this init-state-agnostic
// (poison or zeros). Bounded spins -> wrong answer, never a hang.
__device__ __forceinline__ void gbar(u32* slots, u32* flagline, u32 epoch) {
    u32 tag = TAGBASE + epoch;
    __syncthreads();                       // drains this block's vmem stores
    if (blockIdx.x == 0) {
        int tid = threadIdx.x;
        int guard = 0;
        for (;;) {
            u32 a = ald32(&slots[(1 + tid) << 4]);
            u32 b = (tid < 255) ? ald32(&slots[(257 + tid) << 4]) : tag;
            if (__syncthreads_and((a == tag) && (b == tag))) break;
            __builtin_amdgcn_s_sleep(1);
            if (++guard > (1 << 20)) break;
        }
        if (tid == 0) ast32(flagline, tag);
        __syncthreads();
    } else {
        if (threadIdx.x == 0) {
            ast32(&slots[blockIdx.x << 4], tag);
            int guard = 0;
            while (ald32(flagline) != tag) {
                __builtin_amdgcn_s_sleep(1);
                if (++guard > (1 << 22)) break;
            }
        }
        __syncthreads();
    }
}

// shared box decode — identical FP sequence wherever a box is materialized.
// No FMA contraction (numpy rounds mul and add separately).
__device__ __forceinline__ float4 decode_box(int a, int cell,
                                             const float* __restrict__ deltas,
                                             float info0, float info1, float info2,
                                             bool* valid) {
    int h = cell / Wd;
    int w = cell - h * Wd;
    const float* db = deltas + (size_t)(4 * a) * HW + cell;
    float dx = db[0];
    float dy = db[HW];
    float dw = db[2 * HW];
    float dh = db[3 * HW];
    dw = fminf(fmaxf(dw, -10.f), 10.f);
    dh = fminf(fmaxf(dh, -10.f), 10.f);

    float ww = c_aw[a], hh = c_ah[a];
    float cx = 16.f * (float)w + 8.f;   // exact
    float cy = 16.f * (float)h + 8.f;   // exact

    float pcx = __fadd_rn(__fmul_rn(dx, ww), cx);
    float pcy = __fadd_rn(__fmul_rn(dy, hh), cy);
    float pw  = __fmul_rn(expf(dw), ww);
    float ph  = __fmul_rn(expf(dh), hh);
    float hpw = __fmul_rn(0.5f, pw);
    float hph = __fmul_rn(0.5f, ph);
    float x1 = __fsub_rn(pcx, hpw);
    float x2 = __fadd_rn(pcx, hpw);
    float y1 = __fsub_rn(pcy, hph);
    float y2 = __fadd_rn(pcy, hph);

    float xmax = __fsub_rn(info1, 1.f);
    float ymax = __fsub_rn(info0, 1.f);
    x1 = fminf(fmaxf(x1, 0.f), xmax);
    x2 = fminf(fmaxf(x2, 0.f), xmax);
    y1 = fminf(fmaxf(y1, 0.f), ymax);
    y2 = fminf(fmaxf(y2, 0.f), ymax);

    float msz = __fmul_rn(16.f, info2);
    *valid = (__fadd_rn(__fsub_rn(x2, x1), 1.f) >= msz) &&
             (__fadd_rn(__fsub_rn(y2, y1), 1.f) >= msz);
    return make_float4(x1, y1, x2, y2);
}

// 64-bit readlane, wave-uniform index
__device__ __forceinline__ u64 rdl64(u64 v, int l) {
    u32 lo = (u32)__builtin_amdgcn_readlane((int)(u32)v, l);
    u32 hi = (u32)__builtin_amdgcn_readlane((int)(u32)(v >> 32), l);
    return ((u64)hi << 32) | (u64)lo;
}

__global__ __launch_bounds__(256, 2) void fused_kernel(
        const float* __restrict__ scores, const float* __restrict__ deltas,
        const float* __restrict__ iminfo, float* __restrict__ out,
        u32* __restrict__ slots, u32* __restrict__ flagline, u32* __restrict__ initflag,
        u32* __restrict__ hist1, u32* __restrict__ hist2,
        u32* __restrict__ segctr, u32* __restrict__ validb,
        u32* __restrict__ keys, u64* __restrict__ cand,
        float4* __restrict__ tb, u64* __restrict__ mat) {
    int tid = threadIdx.x;
    int bid = blockIdx.x;
    int lane = tid & 63;
    int wv = tid >> 6;

    __shared__ u32 lh[256];
    __shared__ u32 sfx[256];
    __shared__ u32 h2w[4][256];
    __shared__ u64 stage[2048];          // 16 KB (rank phase)
    __shared__ float4 cbw[4][64];        // matrix phase
    __shared__ int kept[POSTN];          // scan phase
    __shared__ u32 sP, sRank, sT;

    float info0 = iminfo[0], info1 = iminfo[1], info2 = iminfo[2];
    int tbase = bid * PERBLK;            // exactly equal work per block

    // ---------- in-kernel init (block 0): zero accumulators, set initflag ----
    if (bid == 0) {
        ast32(&hist1[tid], 0u);
        ast32(&hist2[tid], 0u);
        ast32(&segctr[tid], 0u);         // 256 u32 covers the 8 spaced counters
        __syncthreads();                 // drain zero-stores
        if (tid == 0) ast32(initflag, INITTAG);
    }

    // ---------- P0: decode keys + per-block LDS hist ----------
    lh[tid] = 0u;
    __syncthreads();
    #pragma unroll
    for (int j = 0; j < 2; ++j) {
        int i = j * 256 + tid;
        if (i < PERBLK) {
            int t = tbase + i;
            int a = t / HW;
            int cell = t - a * HW;
            float score = scores[(AA + a) * HW + cell];
            bool valid;
            (void)decode_box(a, cell, deltas, info0, info1, info2, &valid);
            u32 sb = __float_as_uint(score);
            u32 key = valid ? ((sb & 0x80000000u) ? ~sb : (sb | 0x80000000u))
                            : 0x007FFFFFu;
            ast32(&keys[t], key);
            atomicAdd(&lh[key >> 24], 1u);
        }
    }
    __syncthreads();
    if (tid == 0 && bid != 0) {          // wait for zeroed hists (long since done)
        int guard = 0;
        while (ald32(initflag) != INITTAG) {
            __builtin_amdgcn_s_sleep(1);
            if (++guard > (1 << 22)) break;
        }
    }
    __syncthreads();
    if (lh[tid]) atomicAdd(&hist1[tid], lh[tid]);
    gbar(slots, flagline, 1);

    // ---------- P1 (redundant per block): suffix hist1 -> prefix P, rankP ---
    sfx[tid] = ald32(&hist1[tid]);
    __syncthreads();
    for (int d = 1; d < 256; d <<= 1) {
        u32 v = (tid + d < 256) ? sfx[tid + d] : 0u;
        __syncthreads();
        sfx[tid] += v;
        __syncthreads();
    }
    {
        u32 ge = sfx[tid];
        u32 gt = (tid < 255) ? sfx[tid + 1] : 0u;
        if (ge >= TOPN && gt < TOPN) { sP = (u32)tid; sRank = TOPN - gt; }
    }
    // ---------- P2: second-byte hist of prefix-P keys -> global hist2 -------
    for (int i = tid; i < 4 * 256; i += 256) ((u32*)h2w)[i] = 0u;
    __syncthreads();
    u32 P = sP, rankP = sRank;
    #pragma unroll
    for (int j = 0; j < 2; ++j) {
        int i = j * 256 + tid;
        if (i < PERBLK) {
            u32 k = ald32(&keys[tbase + i]);
            if ((k >> 24) == P) atomicAdd(&h2w[wv][(k >> 16) & 0xFFu], 1u);
        }
    }
    __syncthreads();
    {
        u32 s4 = h2w[0][tid] + h2w[1][tid] + h2w[2][tid] + h2w[3][tid];
        if (s4) atomicAdd(&hist2[tid], s4);
    }
    gbar(slots, flagline, 2);

    // ---------- P3 (redundant per block): suffix hist2 -> threshold T -------
    sfx[tid] = ald32(&hist2[tid]);
    __syncthreads();
    for (int d = 1; d < 256; d <<= 1) {
        u32 v = (tid + d < 256) ? sfx[tid + d] : 0u;
        __syncthreads();
        sfx[tid] += v;
        __syncthreads();
    }
    {
        u32 ge = sfx[tid];
        u32 gt = (tid < 255) ? sfx[tid + 1] : 0u;
        if (ge >= rankP && gt < rankP) sT = (P << 24) | ((u32)tid << 16);
    }
    __syncthreads();
    u32 T = sT;
    // ---------- P4: compact keys >= T into 8 segments ----------
    #pragma unroll
    for (int j = 0; j < 2; ++j) {
        int i = j * 256 + tid;
        if (i < PERBLK) {
            int t = tbase + i;
            u32 k = ald32(&keys[t]);
            if (k >= T) {
                int seg = bid & 7;
                u32 pos = atomicAdd(&segctr[32 * seg], 1u);
                if (pos < SEGSZ) {
                    int a = t / HW;
                    int cell = t - a * HW;
                    u32 aidx = (u32)(cell * 9 + a);
                    ast64(&cand[seg * SEGSZ + pos], ((u64)k << 32) | (u64)(~aidx));
                }
            }
        }
    }
    gbar(slots, flagline, 3);

    // ---------- P5: exact rank + scatter (512 blocks x 16 cand) ----------
    {
        u32 cc[8];
        #pragma unroll
        for (int s = 0; s < 8; ++s) {
            cc[s] = ald32(&segctr[32 * s]);
            if (cc[s] > SEGSZ) cc[s] = SEGSZ;
        }
        int part = tid & 15;
        int i = bid * 16 + (tid >> 4);          // [0, 8192)
        int iseg = i >> 10, ioff = i & 1023;
        bool active = (u32)ioff < cc[iseg];
        u64 k = active ? ald64(&cand[i]) : 0ull;
        u32 cnt = 0;
        for (int q = 0; q < 4; ++q) {
            for (int j = tid; j < 2048; j += 256) {
                int g = q * 2048 + j;
                int s_ = g >> 10, off = g & 1023;
                stage[j] = ((u32)off < cc[s_]) ? ald64(&cand[g]) : 0ull;
            }
            __syncthreads();
            const ulonglong2* sv = (const ulonglong2*)stage;
            for (int jj = part; jj < 1024; jj += 16) {
                ulonglong2 v = sv[jj];
                cnt += (v.x > k) ? 1u : 0u;
                cnt += (v.y > k) ? 1u : 0u;
            }
            __syncthreads();
        }
        cnt += __shfl_xor(cnt, 1);
        cnt += __shfl_xor(cnt, 2);
        cnt += __shfl_xor(cnt, 4);
        cnt += __shfl_xor(cnt, 8);
        if (part == 0 && active && cnt < TOPN) {
            u32 aidx = ~((u32)k);
            int a = (int)(aidx % 9u);
            int cell = (int)(aidx / 9u);
            bool valid;
            float4 box = decode_box(a, cell, deltas, info0, info1, info2, &valid);
            stf4(&tb[cnt], box);
            ast32(&validb[cnt], ((u32)(k >> 32) != 0x007FFFFFu) ? 1u : 0u);
        }
    }
    gbar(slots, flagline, 4);

    // ---------- P6: suppression bit-matrix (upper-triangle tiles) ----------
    {
        int waveid = bid * 4 + wv;
        for (int j = waveid; j < 94 * 94; j += GRID * 4) {
            int by = j / 94;
            int bx = j - by * 94;
            if (bx < by) continue;
            int c0 = bx * 64;
            {
                int col = c0 + lane;
                cbw[wv][lane] = (col < TOPN) ? ldf4(&tb[col]) : make_float4(0.f, 0.f, 0.f, 0.f);
            }
            int row = by * 64 + lane;
            if (row < TOPN) {
                float4 rb = ldf4(&tb[row]);
                float rA = (rb.z - rb.x) * (rb.w - rb.y);
                u64 mask = 0ull;
                for (int c = 0; c < 64; ++c) {
                    if (c0 + c >= TOPN) break;
                    float4 b = cbw[wv][c];
                    float lx = fmaxf(rb.x, b.x), ly = fmaxf(rb.y, b.y);
                    float rx = fminf(rb.z, b.z), ry = fminf(rb.w, b.w);
                    float iw = fmaxf(rx - lx, 0.f), ih = fmaxf(ry - ly, 0.f);
                    float inter = iw * ih;
                    float bA = (b.z - b.x) * (b.w - b.y);
                    float iou = inter / ((rA + bA) - inter);
                    if (iou > 0.7f) mask |= (1ull << c);   // NaN -> false, as numpy
                }
                ast64(&mat[(size_t)row * NW2 + bx], mask);
            }
        }
    }
    gbar(slots, flagline, 5);

    // ---------- P7: greedy scan, 256-box chunks, diag prefetch 1 ahead ------
    if (bid == 0 && tid < 64) {
        // assemble removal words from validb (unwritten pads read != 1 -> removed)
        u64 r0, r1;
        {
            u64 bits = 0ull;
            for (int j = 0; j < 64; ++j)
                if (ald32(&validb[lane * 64 + j]) == 1u) bits |= (1ull << j);
            r0 = ~bits;
            if (lane < NWORDS - 64) {
                u64 bits1 = 0ull;
                for (int j = 0; j < 64; ++j) {
                    int idx = (64 + lane) * 64 + j;
                    if (idx < 6016 && ald32(&validb[idx]) == 1u) bits1 |= (1ull << j);
                }
                r1 = ~bits1;
            } else {
                r1 = ~0ull;
            }
        }
        int cnt = 0;
        u64 dg[4][4];
        #pragma unroll
        for (int q = 0; q < 4; ++q) {
            const u64* rp = mat + (size_t)(q * 64 + lane) * NW2;
            dg[q][0] = ald64(rp); dg[q][1] = ald64(rp + 1);
            dg[q][2] = ald64(rp + 2); dg[q][3] = ald64(rp + 3);
        }
        for (int c = 0; c < NCHUNK; ++c) {
            u64 nd[4][4];
            #pragma unroll
            for (int q = 0; q < 4; ++q) { nd[q][0]=0; nd[q][1]=0; nd[q][2]=0; nd[q][3]=0; }
            if (c + 1 < NCHUNK) {   // unconditional prefetch: off the critical path
                int nb = (c + 1) * 256, nw = 4 * (c + 1);
                #pragma unroll
                for (int q = 0; q < 4; ++q) {
                    const u64* rp = mat + (size_t)(nb + q * 64 + lane) * NW2 + nw;
                    nd[q][0] = ald64(rp); nd[q][1] = ald64(rp + 1);
                    nd[q][2] = ald64(rp + 2); nd[q][3] = ald64(rp + 3);
                }
            }
            int w0 = 4 * c;
            u64 s0 = (w0     < 64) ? rdl64(r0, w0)     : rdl64(r1, w0 - 64);
            u64 s1 = (w0 + 1 < 64) ? rdl64(r0, w0 + 1) : rdl64(r1, w0 - 63);
            u64 s2 = (w0 + 2 < 64) ? rdl64(r0, w0 + 2) : rdl64(r1, w0 - 62);
            u64 s3 = (w0 + 3 < 64) ? rdl64(r0, w0 + 3) : rdl64(r1, w0 - 61);
            if ((s0 & s1 & s2 & s3) != ~0ull) {
                int base = c * 256;
                u64 rem0 = s0, rem1 = s1, rem2 = s2, rem3 = s3;
                u64 km0 = 0, km1 = 0, km2 = 0, km3 = 0;
                while (cnt < POSTN) {
                    int b;
                    if (~rem0) b = __ffsll((u64)~rem0) - 1;
                    else if (~rem1) b = 64  + __ffsll((u64)~rem1) - 1;
                    else if (~rem2) b = 128 + __ffsll((u64)~rem2) - 1;
                    else if (~rem3) b = 192 + __ffsll((u64)~rem3) - 1;
                    else break;
                    if (lane == 0) kept[cnt] = base + b;
                    ++cnt;
                    int q = b >> 6, l = b & 63;
                    u64 v0, v1, v2, v3;
                    if (q == 0)      { v0=dg[0][0]; v1=dg[0][1]; v2=dg[0][2]; v3=dg[0][3]; }
                    else if (q == 1) { v0=dg[1][0]; v1=dg[1][1]; v2=dg[1][2]; v3=dg[1][3]; }
                    else if (q == 2) { v0=dg[2][0]; v1=dg[2][1]; v2=dg[2][2]; v3=dg[2][3]; }
                    else             { v0=dg[3][0]; v1=dg[3][1]; v2=dg[3][2]; v3=dg[3][3]; }
                    rem0 |= rdl64(v0, l); rem1 |= rdl64(v1, l);
                    rem2 |= rdl64(v2, l); rem3 |= rdl64(v3, l);
                    u64 bit = 1ull << l;
                    if (q == 0)      { rem0 |= bit; km0 |= bit; }
                    else if (q == 1) { rem1 |= bit; km1 |= bit; }
                    else if (q == 2) { rem2 |= bit; km2 |= bit; }
                    else             { rem3 |= bit; km3 |= bit; }
                }
                if (cnt >= POSTN) break;
                u64 f0 = 0ull, f1 = 0ull;
                while (km0 | km1 | km2 | km3) {
                    int idx[16];
                    #pragma unroll
                    for (int j = 0; j < 16; ++j) {
                        int b = -1;
                        if (km0)      { b = __ffsll(km0) - 1;        km0 &= km0 - 1; }
                        else if (km1) { b = 64  + __ffsll(km1) - 1;  km1 &= km1 - 1; }
                        else if (km2) { b = 128 + __ffsll(km2) - 1;  km2 &= km2 - 1; }
                        else if (km3) { b = 192 + __ffsll(km3) - 1;  km3 &= km3 - 1; }
                        idx[j] = b;
                    }
                    u64 a0[16], a1[16];
                    #pragma unroll
                    for (int j = 0; j < 16; ++j) {
                        a0[j] = 0ull; a1[j] = 0ull;
                        if (idx[j] >= 0) {
                            const u64* row = mat + (size_t)(base + idx[j]) * NW2;
                            a0[j] = ald64(row + lane);
                            if (lane < NWORDS - 64) a1[j] = ald64(row + 64 + lane);
                        }
                    }
                    #pragma unroll
                    for (int j = 0; j < 16; ++j) { f0 |= a0[j]; f1 |= a1[j]; }
                }
                r0 |= f0; r1 |= f1;
            }
            #pragma unroll
            for (int q = 0; q < 4; ++q) {
                dg[q][0]=nd[q][0]; dg[q][1]=nd[q][1]; dg[q][2]=nd[q][2]; dg[q][3]=nd[q][3];
            }
        }
        for (int r = lane; r < POSTN; r += 64) {
            float4 b2 = make_float4(0.f, 0.f, 0.f, 0.f);
            if (r < cnt) b2 = ldf4(&tb[kept[r]]);
            float* o = out + r * 5;
            o[0] = 0.f; o[1] = b2.x; o[2] = b2.y; o[3] = b2.z; o[4] = b2.w;
        }
    }
}

// ---------------- host launcher ----------------
extern "C" void kernel_launch(void* const* d_in, const int* in_sizes, int n_in,
                              void* d_out, int out_size, void* d_ws, size_t ws_size,
                              hipStream_t stream) {
    const float* scores = (const float*)d_in[0];
    const float* deltas = (const float*)d_in[1];
    const float* iminfo = (const float*)d_in[2];
    float* out = (float*)d_out;

    char* ws = (char*)d_ws;
    // all state is init-agnostic (exact-match tags / in-kernel zeroing) -> no memset
    u32* slots    = (u32*)(ws + 0);          // 512 slots x 64B = 32768
    u32* flagline = (u32*)(ws + 32768);      // 64
    u32* initflag = (u32*)(ws + 32832);      // 64
    u32* hist1    = (u32*)(ws + 32896);      // 1024
    u32* hist2    = (u32*)(ws + 33920);      // 1024
    u32* segctr   = (u32*)(ws + 34944);      // 1024 (8 ctrs, 128B apart)
    u32* validb   = (u32*)(ws + 35968);      // 6016*4 = 24064
    u32* keys     = (u32*)(ws + 60032);      // 884736
    u64* cand     = (u64*)(ws + 944768);     // 65536
    float4* tb    = (float4*)(ws + 1010304); // 96256
    u64* mat      = (u64*)(ws + 1106560);    // 6144*96*8 = 4718592 -> ends 5825152

    fused_kernel<<<GRID, 256, 0, stream>>>(scores, deltas, iminfo, out,
                                           slots, flagline, initflag,
                                           hist1, hist2, segctr, validb,
                                           keys, cand, tb, mat);
}